// Round 14
// baseline (168.992 us; speedup 1.0000x reference)
//
#include <hip/hip_runtime.h>
#include <hip/hip_cooperative_groups.h>
#include <math.h>

namespace cg = cooperative_groups;

typedef __attribute__((ext_vector_type(4))) double d4;

// order-preserving float -> uint key (ascending float => ascending uint)
__device__ inline unsigned fkey(float f) {
  unsigned bits = __float_as_uint(f);
  return (bits & 0x80000000u) ? ~bits : (bits | 0x80000000u);
}

#define STORE4D(base, off, v)                          \
  {                                                    \
    double* _p = (base) + (off);                       \
    _p[0] = (double)(v).x; _p[1] = (double)(v).y;      \
    _p[2] = (double)(v).z; _p[3] = (double)(v).w;      \
  }

// ---------------------------------------------------------------------------
// Kernel 1 (round-13 proven, UNCHANGED): fused {probe, fp64-MFMA GEMM}.
// ---------------------------------------------------------------------------
__global__ __launch_bounds__(512, 4) void logits_fused_kernel(
    const float* __restrict__ x, const float* __restrict__ W,
    const float* __restrict__ bias, float* __restrict__ logits,
    float* __restrict__ logitsT, int N, int D) {
  __shared__ __attribute__((aligned(16))) double xbuf[2][64 * 33];
  __shared__ __attribute__((aligned(16))) double wbuf[2][64 * 33];
  __shared__ unsigned s_fl;

  const int tid = threadIdx.x;
  const int tok0 = blockIdx.x * 64;
  const int l = tid & 63;
  const int l15 = l & 15;
  const int lk = l >> 4;

  // ---- fused probe: wave 0, scratch in wbuf ----
  double* pA = &wbuf[0][0];        // [16][4]
  double* pB = &wbuf[0][64];       // [4][16]
  if (tid < 64) {
    pA[l15 * 4 + lk] = (double)(l15 * 4 + lk + 1);
    pB[lk * 16 + l15] = (double)(l15 * 7 + lk * 3 + 2);
  }
  __syncthreads();
  if (tid < 64) {
    double a = pA[l15 * 4 + lk];
    double b = pB[lk * 16 + l15];
    d4 pacc = (d4)0.0;
    pacc = __builtin_amdgcn_mfma_f64_16x16x4f64(a, b, pacc, 0, 0, 0);
    unsigned res = 4;
    for (int m = 3; m >= 0; --m) {
      bool ok = true;
#pragma unroll
      for (int i = 0; i < 4; ++i) {
        int tr_ = (m < 2) ? ((m == 0) ? 4 * lk + i : lk + 4 * i) : l15;
        int tc_ = (m < 2) ? l15 : ((m == 2) ? 4 * lk + i : lk + 4 * i);
        double ref = 0.0;
#pragma unroll
        for (int kk = 0; kk < 4; ++kk) ref += pA[tr_ * 4 + kk] * pB[kk * 16 + tc_];
        ok = ok && (pacc[i] == ref);
      }
      if (__all(ok)) res = (unsigned)m;
    }
    if (l == 0) s_fl = res;
  }
  __syncthreads();
  const unsigned fl = s_fl;
  __syncthreads();   // probe scratch dead before staging reuses wbuf

  if (fl < 4u) {
    const int w = tid >> 6;        // wave 0..7
    const int rb = (w & 3) * 16;   // token-row base
    const int cb = (w >> 2) * 32;  // expert-col base

    d4 acc0 = (d4)0.0;
    d4 acc1 = (d4)0.0;

    const int srow = tid >> 3;           // 0..63
    const int sc = tid & 7;              // quad 0..7
    const float* gx = x + (size_t)(tok0 + srow) * D + sc * 4;
    const float* gw = W + (size_t)srow * D + sc * 4;
    const int lo = srow * 33 + sc * 4;

    const int nch = D >> 5;              // 32 chunks
    const int xa0 = (rb + l15) * 33 + lk;
    const int ba0 = (cb + l15) * 33 + lk;

    float4 rx = *(const float4*)gx;
    float4 rw = *(const float4*)gw;
    STORE4D(&xbuf[0][0], lo, rx);
    STORE4D(&wbuf[0][0], lo, rw);
    if (nch > 1) {
      rx = *(const float4*)(gx + 32);
      rw = *(const float4*)(gw + 32);
    }
    __syncthreads();

    for (int c = 0; c < nch; ++c) {
      const int cbuf = c & 1;
      const int nb = cbuf ^ 1;
      if (c + 1 < nch) {
        STORE4D(&xbuf[nb][0], lo, rx);
        STORE4D(&wbuf[nb][0], lo, rw);
        if (c + 2 < nch) {
          rx = *(const float4*)(gx + (c + 2) * 32);
          rw = *(const float4*)(gw + (c + 2) * 32);
        }
      }
      const double* xr = &xbuf[cbuf][0];
      const double* wr = &wbuf[cbuf][0];
      double a[8], b0[8], b1[8];
#pragma unroll
      for (int s = 0; s < 8; ++s) {
        a[s]  = xr[xa0 + 4 * s];
        b0[s] = wr[ba0 + 4 * s];
        b1[s] = wr[ba0 + 16 * 33 + 4 * s];
      }
#pragma unroll
      for (int s = 0; s < 8; ++s) {
        acc0 = __builtin_amdgcn_mfma_f64_16x16x4f64(a[s], b0[s], acc0, 0, 0, 0);
        acc1 = __builtin_amdgcn_mfma_f64_16x16x4f64(a[s], b1[s], acc1, 0, 0, 0);
      }
      __syncthreads();
    }

    // ---- epilogue: probed D mapping, bias add (fp64), LDS round-trip ----
    float* ls = (float*)&xbuf[0][0];  // [64][68] fp32 view
#pragma unroll
    for (int ct = 0; ct < 2; ++ct) {
      const d4* ac = (ct == 0) ? &acc0 : &acc1;
#pragma unroll
      for (int i = 0; i < 4; ++i) {
        int tr_, tc_;
        if (fl < 2u) { tc_ = l15; tr_ = (fl == 0u) ? 4 * lk + i : lk + 4 * i; }
        else         { tr_ = l15; tc_ = (fl == 2u) ? 4 * lk + i : lk + 4 * i; }
        int col = cb + ct * 16 + tc_;
        ls[(rb + tr_) * 68 + col] = (float)((*ac)[i] + (double)bias[col]);
      }
    }
    __syncthreads();
#pragma unroll
    for (int it = 0; it < 2; ++it) {   // row-major stores
      int slot = it * 512 + tid;
      int row = slot >> 4, c4 = slot & 15;
      float4 v = {ls[row * 68 + c4 * 4 + 0], ls[row * 68 + c4 * 4 + 1],
                  ls[row * 68 + c4 * 4 + 2], ls[row * 68 + c4 * 4 + 3]};
      *(float4*)(logits + (size_t)(tok0 + row) * 64 + c4 * 4) = v;
    }
#pragma unroll
    for (int it = 0; it < 2; ++it) {   // transposed stores
      int slot = it * 512 + tid;
      int e = slot >> 4, t4 = slot & 15;
      float4 v = {ls[(t4 * 4 + 0) * 68 + e], ls[(t4 * 4 + 1) * 68 + e],
                  ls[(t4 * 4 + 2) * 68 + e], ls[(t4 * 4 + 3) * 68 + e]};
      *(float4*)(logitsT + (size_t)e * N + tok0 + t4 * 4) = v;
    }
  } else {
    // inline VALU fp64 fallback (never expected)
    for (int o = tid; o < 64 * 64; o += 512) {
      int row = o >> 6, col = o & 63;
      const float* xp = x + (size_t)(tok0 + row) * D;
      const float* wp = W + (size_t)col * D;
      double s = 0.0;
      for (int kk = 0; kk < D; ++kk)
        s = fma((double)xp[kk], (double)wp[kk], s);
      float v = (float)(s + (double)bias[col]);
      logits[(size_t)(tok0 + row) * 64 + col] = v;
      logitsT[(size_t)col * N + tok0 + row] = v;
    }
  }
}

// ---------------------------------------------------------------------------
// Cooperative TAIL kernel (N==32768, E==64 only): 64 blocks x 1024 thr.
//  phase 1: per-expert radix select (r11-proven code) -> ukeys[e]
//  phase 2: assign (block b owns tokens b*512..+511; coalesced logitsT
//           reads per expert row; branchless key-max, ascending-e strict->
//           = min-expert tie-break) + per-block LDS count -> global gz
//  phase 3: block 0 computes load-balance loss.
// gz[0..63]=counts, gz[64] unused; zeroed by block 0 in phase 1.
// ---------------------------------------------------------------------------
__global__ __launch_bounds__(1024) void tail_coop_kernel(
    const float* __restrict__ logitsT, float* __restrict__ out,
    unsigned* __restrict__ ukeys, unsigned* __restrict__ gz,
    int N, int k) {
  __shared__ unsigned hist[16][256];
  __shared__ unsigned s_prefix, s_rem;
  __shared__ unsigned uk_lds[64];
  __shared__ unsigned cnt[64];
  const int e = blockIdx.x;
  const int tid = threadIdx.x;
  const int wid = tid >> 6;

  if (e == 0 && tid < 65) gz[tid] = 0u;

  // ================= phase 1: select =================
  const float4* src = (const float4*)(logitsT + (size_t)e * N);
  unsigned key[32];
#pragma unroll
  for (int i = 0; i < 8; ++i) {
    float4 v = src[tid + i * 1024];
    key[i * 4 + 0] = fkey(v.x);
    key[i * 4 + 1] = fkey(v.y);
    key[i * 4 + 2] = fkey(v.z);
    key[i * 4 + 3] = fkey(v.w);
  }
  if (tid == 0) { s_prefix = 0u; s_rem = (unsigned)k; }

  for (int r = 0; r < 4; ++r) {
    const int shift = 24 - 8 * r;
    const unsigned maskhi = (r == 0) ? 0u : (0xFFFFFFFFu << (shift + 8));
#pragma unroll
    for (int z = 0; z < 4; ++z) ((unsigned*)hist)[z * 1024 + tid] = 0u;
    __syncthreads();
    const unsigned prefix = s_prefix;
#pragma unroll
    for (int i = 0; i < 32; ++i) {
      unsigned u = key[i];
      if ((u & maskhi) == prefix)
        atomicAdd(&hist[wid][(u >> shift) & 255u], 1u);
    }
    __syncthreads();
    if (tid < 64) {
      unsigned rem = s_rem;
      unsigned h0 = 0, h1 = 0, h2 = 0, h3 = 0;
#pragma unroll
      for (int w = 0; w < 16; ++w) {
        h0 += hist[w][tid * 4 + 0];
        h1 += hist[w][tid * 4 + 1];
        h2 += hist[w][tid * 4 + 2];
        h3 += hist[w][tid * 4 + 3];
      }
      unsigned c3 = h3, c2 = c3 + h2, c1 = c2 + h1, c0 = c1 + h0;
      unsigned cum = c0;
#pragma unroll
      for (int off = 1; off < 64; off <<= 1) {
        unsigned v = __shfl_down(cum, off);
        if (tid + off < 64) cum += v;
      }
      unsigned above = cum - c0;
      if (above < rem && rem <= cum) {
        int j; unsigned abv;
        if (above + c3 >= rem)      { j = 3; abv = above; }
        else if (above + c2 >= rem) { j = 2; abv = above + c3; }
        else if (above + c1 >= rem) { j = 1; abv = above + c2; }
        else                        { j = 0; abv = above + c1; }
        s_rem = rem - abv;
        s_prefix = prefix | ((unsigned)(tid * 4 + j) << shift);
      }
    }
    __syncthreads();
  }
  if (tid == 0) ukeys[e] = s_prefix;
  __threadfence();
  cg::this_grid().sync();

  // ================= phase 2: assign + count =================
  if (tid < 64) { uk_lds[tid] = ukeys[tid]; cnt[tid] = 0u; }
  __syncthreads();
  if (tid < 512) {
    const int token = blockIdx.x * 512 + tid;
    unsigned bu = 0u; int be = -1; float bv = 0.0f;
#pragma unroll 8
    for (int ee = 0; ee < 64; ++ee) {
      float v = logitsT[(size_t)ee * N + token];
      unsigned u = fkey(v);
      unsigned uu = (u >= uk_lds[ee]) ? u : 0u;  // finite floats: key > 0
      if (uu > bu) { bu = uu; be = ee; bv = v; }
    }
    const bool sel = (bu != 0u);
    out[token] = sel ? bv : 0.0f;
    out[N + token] = (float)be;
    out[2 * N + token] = sel ? 1.0f : 0.0f;
    if (sel) atomicAdd(&cnt[be], 1u);
  }
  __syncthreads();
  if (tid < 64 && cnt[tid]) atomicAdd(&gz[tid], cnt[tid]);
  __threadfence();
  cg::this_grid().sync();

  // ================= phase 3: loss (block 0) =================
  if (blockIdx.x == 0 && tid < 64) {
    unsigned c = atomicAdd(&gz[tid], 0u);   // coherent device-scope read
    double cd = (double)c;
    double s = cd;
#pragma unroll
    for (int off = 32; off; off >>= 1) s += __shfl_xor(s, off);
    double mean = s / 64.0;
    double d = cd - mean;
    d = d * d;
#pragma unroll
    for (int off = 32; off; off >>= 1) d += __shfl_xor(d, off);
    if (tid == 0) out[3 * (size_t)N] = (float)((d / 64.0) / (mean + 1e-9));
  }
}

// ---------------------------------------------------------------------------
// Fallback tail kernels (round-11/8 proven), used if cooperative launch
// is unavailable or shape differs.
// ---------------------------------------------------------------------------
template <int KPT4>
__global__ __launch_bounds__(1024) void select_kernel(
    const float* __restrict__ logitsT, unsigned* __restrict__ ukeys,
    int N, int k) {
  __shared__ unsigned hist[16][256];
  __shared__ unsigned s_prefix, s_rem;
  const int e = blockIdx.x;
  const int tid = threadIdx.x;
  const int wid = tid >> 6;

  const float4* src = (const float4*)(logitsT + (size_t)e * N);
  unsigned key[KPT4 > 0 ? KPT4 * 4 : 4];
  if (KPT4 > 0) {
#pragma unroll
    for (int i = 0; i < (KPT4 > 0 ? KPT4 : 1); ++i) {
      float4 v = src[tid + i * 1024];
      key[i * 4 + 0] = fkey(v.x);
      key[i * 4 + 1] = fkey(v.y);
      key[i * 4 + 2] = fkey(v.z);
      key[i * 4 + 3] = fkey(v.w);
    }
  }
  if (tid == 0) { s_prefix = 0u; s_rem = (unsigned)k; }

  for (int r = 0; r < 4; ++r) {
    const int shift = 24 - 8 * r;
    const unsigned maskhi = (r == 0) ? 0u : (0xFFFFFFFFu << (shift + 8));
#pragma unroll
    for (int z = 0; z < 4; ++z) ((unsigned*)hist)[z * 1024 + tid] = 0u;
    __syncthreads();
    const unsigned prefix = s_prefix;
    if (KPT4 > 0) {
#pragma unroll
      for (int i = 0; i < (KPT4 > 0 ? KPT4 * 4 : 1); ++i) {
        unsigned u = key[i];
        if ((u & maskhi) == prefix)
          atomicAdd(&hist[wid][(u >> shift) & 255u], 1u);
      }
    } else {
      for (int i = tid; i < (N >> 2); i += 1024) {
        float4 v = src[i];
        unsigned u0 = fkey(v.x), u1 = fkey(v.y), u2 = fkey(v.z), u3 = fkey(v.w);
        if ((u0 & maskhi) == prefix) atomicAdd(&hist[wid][(u0 >> shift) & 255u], 1u);
        if ((u1 & maskhi) == prefix) atomicAdd(&hist[wid][(u1 >> shift) & 255u], 1u);
        if ((u2 & maskhi) == prefix) atomicAdd(&hist[wid][(u2 >> shift) & 255u], 1u);
        if ((u3 & maskhi) == prefix) atomicAdd(&hist[wid][(u3 >> shift) & 255u], 1u);
      }
    }
    __syncthreads();
    if (tid < 64) {
      unsigned rem = s_rem;
      unsigned h0 = 0, h1 = 0, h2 = 0, h3 = 0;
#pragma unroll
      for (int w = 0; w < 16; ++w) {
        h0 += hist[w][tid * 4 + 0];
        h1 += hist[w][tid * 4 + 1];
        h2 += hist[w][tid * 4 + 2];
        h3 += hist[w][tid * 4 + 3];
      }
      unsigned c3 = h3, c2 = c3 + h2, c1 = c2 + h1, c0 = c1 + h0;
      unsigned cum = c0;
#pragma unroll
      for (int off = 1; off < 64; off <<= 1) {
        unsigned v = __shfl_down(cum, off);
        if (tid + off < 64) cum += v;
      }
      unsigned above = cum - c0;
      if (above < rem && rem <= cum) {
        int j; unsigned abv;
        if (above + c3 >= rem)      { j = 3; abv = above; }
        else if (above + c2 >= rem) { j = 2; abv = above + c3; }
        else if (above + c1 >= rem) { j = 1; abv = above + c2; }
        else                        { j = 0; abv = above + c1; }
        s_rem = rem - abv;
        s_prefix = prefix | ((unsigned)(tid * 4 + j) << shift);
      }
    }
    __syncthreads();
  }
  if (tid == 0) ukeys[e] = s_prefix;
}

__global__ __launch_bounds__(256) void assign_kernel(
    const float* __restrict__ logits, const unsigned* __restrict__ ukeys,
    float* __restrict__ out, int N) {
  const int lane = threadIdx.x & 63;
  const int token = blockIdx.x * 4 + (threadIdx.x >> 6);

  float v = logits[(size_t)token * 64 + lane];
  unsigned u = fkey(v);
  bool cand = (u >= ukeys[lane]);
  float cv = cand ? v : -INFINITY;
  float m = cv;
#pragma unroll
  for (int off = 32; off; off >>= 1) m = fmaxf(m, __shfl_xor(m, off));
  unsigned long long mask = __ballot(cand && (v == m));
  bool sel = (mask != 0ull);
  int minexp = sel ? (__ffsll((long long)mask) - 1) : -1;

  if (lane == 0) {
    out[token] = sel ? m : 0.0f;
    out[N + token] = (float)minexp;
    out[2 * N + token] = sel ? 1.0f : 0.0f;
  }
}

__global__ __launch_bounds__(1024) void count_loss_kernel(
    const float* __restrict__ assigned, float* __restrict__ out, int N) {
  __shared__ unsigned hist[16][64];
  const int tid = threadIdx.x;
  const int wid = tid >> 6;
  hist[wid][tid & 63] = 0u;
  __syncthreads();
  const float4* src = (const float4*)assigned;
  for (int i = tid; i < (N >> 2); i += 1024) {
    float4 v = src[i];
    int e0 = (int)v.x, e1 = (int)v.y, e2 = (int)v.z, e3 = (int)v.w;
    if (e0 >= 0) atomicAdd(&hist[wid][e0], 1u);
    if (e1 >= 0) atomicAdd(&hist[wid][e1], 1u);
    if (e2 >= 0) atomicAdd(&hist[wid][e2], 1u);
    if (e3 >= 0) atomicAdd(&hist[wid][e3], 1u);
  }
  __syncthreads();
  if (tid < 64) {
    unsigned c = 0;
#pragma unroll
    for (int w = 0; w < 16; ++w) c += hist[w][tid];
    double cd = (double)c;
    double s = cd;
#pragma unroll
    for (int off = 32; off; off >>= 1) s += __shfl_xor(s, off);
    double mean = s / 64.0;
    double d = cd - mean;
    d = d * d;
#pragma unroll
    for (int off = 32; off; off >>= 1) d += __shfl_xor(d, off);
    if (tid == 0) out[3 * (size_t)N] = (float)((d / 64.0) / (mean + 1e-9));
  }
}

extern "C" void kernel_launch(void* const* d_in, const int* in_sizes, int n_in,
                              void* d_out, int out_size, void* d_ws, size_t ws_size,
                              hipStream_t stream) {
  const float* x = (const float*)d_in[0];
  const float* W = (const float*)d_in[1];
  const float* b = (const float*)d_in[2];

  const int E = in_sizes[2];      // 64
  const int D = in_sizes[1] / E;  // 1024
  const int N = in_sizes[0] / D;  // 32768

  int k = (int)((double)N / (double)(E > 1 ? E : 1) * 1.2);
  if (k < 1) k = 1;
  if (k > N) k = N;               // 614

  const size_t NE = (size_t)N * E;
  float* out = (float*)d_out;

  float* logits = (float*)d_ws;        // N*E fp32 (8 MB)
  float* logitsT = logits + NE;        // N*E fp32 (8 MB)
  unsigned* ukeys = (unsigned*)(logitsT + NE);
  unsigned* gz = ukeys + 64;           // 65 words

  logits_fused_kernel<<<N / 64, 512, 0, stream>>>(x, W, b, logits, logitsT,
                                                  N, D);

  bool coop_done = false;
  if (N == 32768 && E == 64) {
    void* args[] = {(void*)&logitsT, (void*)&out, (void*)&ukeys,
                    (void*)&gz, (void*)&N, (void*)&k};
    hipError_t err = hipLaunchCooperativeKernel(
        (const void*)tail_coop_kernel, dim3(64), dim3(1024), args, 0, stream);
    if (err == hipSuccess) coop_done = true;
  }
  if (!coop_done) {
    if (N == 32768)
      select_kernel<8><<<64, 1024, 0, stream>>>(logitsT, ukeys, N, k);
    else
      select_kernel<0><<<64, 1024, 0, stream>>>(logitsT, ukeys, N, k);
    assign_kernel<<<N / 4, 256, 0, stream>>>(logits, ukeys, out, N);
    count_loss_kernel<<<1, 1024, 0, stream>>>(out + N, out, N);
  }
}

// Round 15
// 110.459 us; speedup vs baseline: 1.5299x; 1.5299x over previous
//
#include <hip/hip_runtime.h>
#include <math.h>

typedef __attribute__((ext_vector_type(4))) double d4;

// order-preserving float -> uint key (ascending float => ascending uint)
__device__ inline unsigned fkey(float f) {
  unsigned bits = __float_as_uint(f);
  return (bits & 0x80000000u) ? ~bits : (bits | 0x80000000u);
}

// ---------------------------------------------------------------------------
// Kernel 1 (round-10/11 measured best: 86.3-86.7 us): fused {probe, fp64-MFMA
// GEMM} -> logits & logitsT.
// 1024 thr = 16 waves; wave w owns 16x16 tile; DC=32 fp64 LDS chunks,
// row stride 33 (bank-exact), double-buffered, one barrier per chunk.
// ---------------------------------------------------------------------------
__global__ __launch_bounds__(1024, 8) void logits_fused_kernel(
    const float* __restrict__ x, const float* __restrict__ W,
    const float* __restrict__ bias, float* __restrict__ logits,
    float* __restrict__ logitsT, int N, int D) {
  __shared__ __attribute__((aligned(16))) double xbuf[2][64 * 33];
  __shared__ __attribute__((aligned(16))) double wbuf[2][64 * 33];
  __shared__ unsigned s_fl;

  const int tid = threadIdx.x;
  const int tok0 = blockIdx.x * 64;
  const int l = tid & 63;
  const int l15 = l & 15;
  const int lk = l >> 4;

  // ---- fused probe: wave 0, scratch in wbuf ----
  double* pA = &wbuf[0][0];        // [16][4]
  double* pB = &wbuf[0][64];       // [4][16]
  if (tid < 64) {
    pA[l15 * 4 + lk] = (double)(l15 * 4 + lk + 1);
    pB[lk * 16 + l15] = (double)(l15 * 7 + lk * 3 + 2);
  }
  __syncthreads();
  if (tid < 64) {
    double a = pA[l15 * 4 + lk];
    double b = pB[lk * 16 + l15];
    d4 pacc = (d4)0.0;
    pacc = __builtin_amdgcn_mfma_f64_16x16x4f64(a, b, pacc, 0, 0, 0);
    unsigned res = 4;
    for (int m = 3; m >= 0; --m) {
      bool ok = true;
#pragma unroll
      for (int i = 0; i < 4; ++i) {
        int tr_ = (m < 2) ? ((m == 0) ? 4 * lk + i : lk + 4 * i) : l15;
        int tc_ = (m < 2) ? l15 : ((m == 2) ? 4 * lk + i : lk + 4 * i);
        double ref = 0.0;
#pragma unroll
        for (int kk = 0; kk < 4; ++kk) ref += pA[tr_ * 4 + kk] * pB[kk * 16 + tc_];
        ok = ok && (pacc[i] == ref);
      }
      if (__all(ok)) res = (unsigned)m;
    }
    if (l == 0) s_fl = res;
  }
  __syncthreads();
  const unsigned fl = s_fl;
  __syncthreads();   // probe scratch dead before staging reuses wbuf

  if (fl < 4u) {
    const int w = tid >> 6;        // wave 0..15
    const int rb = (w & 3) * 16;   // token-row base
    const int cb = (w >> 2) * 16;  // expert-col base

    d4 acc = (d4)0.0;

    // staging: tid<512 -> x-tile, tid>=512 -> W-tile; 1 float4/thread/chunk
    const int srow = (tid & 511) >> 3;   // 0..63
    const int sc = tid & 7;              // quad 0..7
    const bool isx = (tid < 512);
    const float* gsrc = isx ? (x + (size_t)(tok0 + srow) * D + sc * 4)
                            : (W + (size_t)srow * D + sc * 4);
    const int ldoff = srow * 33 + sc * 4;

    const int nch = D >> 5;              // 32 chunks
    const int xa0 = (rb + l15) * 33 + lk;
    const int ba0 = (cb + l15) * 33 + lk;

    // prologue: chunk 0 -> buf0; prefetch chunk 1
    float4 rg = *(const float4*)gsrc;
    {
      double* ld = (isx ? &xbuf[0][0] : &wbuf[0][0]) + ldoff;
      ld[0] = (double)rg.x; ld[1] = (double)rg.y;
      ld[2] = (double)rg.z; ld[3] = (double)rg.w;
    }
    if (nch > 1) rg = *(const float4*)(gsrc + 32);
    __syncthreads();

    for (int c = 0; c < nch; ++c) {
      const int cbuf = c & 1;
      const int nb = cbuf ^ 1;
      if (c + 1 < nch) {
        double* ld = (isx ? &xbuf[nb][0] : &wbuf[nb][0]) + ldoff;
        ld[0] = (double)rg.x; ld[1] = (double)rg.y;
        ld[2] = (double)rg.z; ld[3] = (double)rg.w;
        if (c + 2 < nch) rg = *(const float4*)(gsrc + (c + 2) * 32);
      }
      const double* xr = &xbuf[cbuf][0];
      const double* wr = &wbuf[cbuf][0];
#pragma unroll
      for (int s = 0; s < 8; ++s) {
        double a = xr[xa0 + 4 * s];
        double b = wr[ba0 + 4 * s];
        acc = __builtin_amdgcn_mfma_f64_16x16x4f64(a, b, acc, 0, 0, 0);
      }
      __syncthreads();
    }

    // ---- epilogue: probed D mapping, bias add (fp64), LDS round-trip ----
    float* ls = (float*)&xbuf[0][0];  // [64][68] fp32 view
#pragma unroll
    for (int i = 0; i < 4; ++i) {
      int tr_, tc_;
      if (fl < 2u) { tc_ = l15; tr_ = (fl == 0u) ? 4 * lk + i : lk + 4 * i; }
      else         { tr_ = l15; tc_ = (fl == 2u) ? 4 * lk + i : lk + 4 * i; }
      int col = cb + tc_;
      ls[(rb + tr_) * 68 + col] = (float)(acc[i] + (double)bias[col]);
    }
    __syncthreads();
    {  // row-major stores: 1024 slots, 1/thread
      int row = tid >> 4, c4 = tid & 15;
      float4 v = {ls[row * 68 + c4 * 4 + 0], ls[row * 68 + c4 * 4 + 1],
                  ls[row * 68 + c4 * 4 + 2], ls[row * 68 + c4 * 4 + 3]};
      *(float4*)(logits + (size_t)(tok0 + row) * 64 + c4 * 4) = v;
    }
    {  // transposed stores: 1/thread
      int e = tid >> 4, t4 = tid & 15;
      float4 v = {ls[(t4 * 4 + 0) * 68 + e], ls[(t4 * 4 + 1) * 68 + e],
                  ls[(t4 * 4 + 2) * 68 + e], ls[(t4 * 4 + 3) * 68 + e]};
      *(float4*)(logitsT + (size_t)e * N + tok0 + t4 * 4) = v;
    }
  } else {
    // inline VALU fp64 fallback (never expected)
    for (int o = tid; o < 64 * 64; o += 1024) {
      int row = o >> 6, col = o & 63;
      const float* xp = x + (size_t)(tok0 + row) * D;
      const float* wp = W + (size_t)col * D;
      double s = 0.0;
      for (int kk = 0; kk < D; ++kk)
        s = fma((double)xp[kk], (double)wp[kk], s);
      float v = (float)(s + (double)bias[col]);
      logits[(size_t)(tok0 + row) * 64 + col] = v;
      logitsT[(size_t)col * N + tok0 + row] = v;
    }
  }
}

// ---------------------------------------------------------------------------
// Kernel 2 (round-11 proven): per-expert k-th-largest via FOUR 8-bit radix
// passes over register-resident keys; per-wave replicated LDS histograms;
// descending scan via 64-lane shuffle suffix-scan.
// ---------------------------------------------------------------------------
template <int KPT4>
__global__ __launch_bounds__(1024) void select_kernel(
    const float* __restrict__ logitsT, unsigned* __restrict__ ukeys,
    int N, int k) {
  __shared__ unsigned hist[16][256];
  __shared__ unsigned s_prefix, s_rem;
  const int e = blockIdx.x;
  const int tid = threadIdx.x;
  const int wid = tid >> 6;

  const float4* src = (const float4*)(logitsT + (size_t)e * N);
  unsigned key[KPT4 > 0 ? KPT4 * 4 : 4];
  if (KPT4 > 0) {
#pragma unroll
    for (int i = 0; i < (KPT4 > 0 ? KPT4 : 1); ++i) {
      float4 v = src[tid + i * 1024];
      key[i * 4 + 0] = fkey(v.x);
      key[i * 4 + 1] = fkey(v.y);
      key[i * 4 + 2] = fkey(v.z);
      key[i * 4 + 3] = fkey(v.w);
    }
  }
  if (tid == 0) { s_prefix = 0u; s_rem = (unsigned)k; }

  for (int r = 0; r < 4; ++r) {
    const int shift = 24 - 8 * r;
    const unsigned maskhi = (r == 0) ? 0u : (0xFFFFFFFFu << (shift + 8));
#pragma unroll
    for (int z = 0; z < 4; ++z) ((unsigned*)hist)[z * 1024 + tid] = 0u;
    __syncthreads();
    const unsigned prefix = s_prefix;
    if (KPT4 > 0) {
#pragma unroll
      for (int i = 0; i < (KPT4 > 0 ? KPT4 * 4 : 1); ++i) {
        unsigned u = key[i];
        if ((u & maskhi) == prefix)
          atomicAdd(&hist[wid][(u >> shift) & 255u], 1u);
      }
    } else {
      for (int i = tid; i < (N >> 2); i += 1024) {
        float4 v = src[i];
        unsigned u0 = fkey(v.x), u1 = fkey(v.y), u2 = fkey(v.z), u3 = fkey(v.w);
        if ((u0 & maskhi) == prefix) atomicAdd(&hist[wid][(u0 >> shift) & 255u], 1u);
        if ((u1 & maskhi) == prefix) atomicAdd(&hist[wid][(u1 >> shift) & 255u], 1u);
        if ((u2 & maskhi) == prefix) atomicAdd(&hist[wid][(u2 >> shift) & 255u], 1u);
        if ((u3 & maskhi) == prefix) atomicAdd(&hist[wid][(u3 >> shift) & 255u], 1u);
      }
    }
    __syncthreads();
    if (tid < 64) {
      unsigned rem = s_rem;
      unsigned h0 = 0, h1 = 0, h2 = 0, h3 = 0;
#pragma unroll
      for (int w = 0; w < 16; ++w) {
        h0 += hist[w][tid * 4 + 0];
        h1 += hist[w][tid * 4 + 1];
        h2 += hist[w][tid * 4 + 2];
        h3 += hist[w][tid * 4 + 3];
      }
      unsigned c3 = h3, c2 = c3 + h2, c1 = c2 + h1, c0 = c1 + h0;
      unsigned cum = c0;
#pragma unroll
      for (int off = 1; off < 64; off <<= 1) {
        unsigned v = __shfl_down(cum, off);
        if (tid + off < 64) cum += v;
      }
      unsigned above = cum - c0;
      if (above < rem && rem <= cum) {
        int j; unsigned abv;
        if (above + c3 >= rem)      { j = 3; abv = above; }
        else if (above + c2 >= rem) { j = 2; abv = above + c3; }
        else if (above + c1 >= rem) { j = 1; abv = above + c2; }
        else                        { j = 0; abv = above + c1; }
        s_rem = rem - abv;
        s_prefix = prefix | ((unsigned)(tid * 4 + j) << shift);
      }
    }
    __syncthreads();
  }
  if (tid == 0) ukeys[e] = s_prefix;
}

// ---------------------------------------------------------------------------
// Kernel 3 (round-8 proven): one wave per token; lane = expert.
// ---------------------------------------------------------------------------
__global__ __launch_bounds__(256) void assign_kernel(
    const float* __restrict__ logits, const unsigned* __restrict__ ukeys,
    float* __restrict__ out, int N) {
  const int lane = threadIdx.x & 63;
  const int token = blockIdx.x * 4 + (threadIdx.x >> 6);

  float v = logits[(size_t)token * 64 + lane];
  unsigned u = fkey(v);
  bool cand = (u >= ukeys[lane]);
  float cv = cand ? v : -INFINITY;
  float m = cv;
#pragma unroll
  for (int off = 32; off; off >>= 1) m = fmaxf(m, __shfl_xor(m, off));
  unsigned long long mask = __ballot(cand && (v == m));
  bool sel = (mask != 0ull);
  int minexp = sel ? (__ffsll((long long)mask) - 1) : -1;

  if (lane == 0) {
    out[token] = sel ? m : 0.0f;
    out[N + token] = (float)minexp;
    out[2 * N + token] = sel ? 1.0f : 0.0f;
  }
}

// ---------------------------------------------------------------------------
// Kernel 4 (round-8 proven): counts (LDS histogram, 1 block, float4) + loss.
// ---------------------------------------------------------------------------
__global__ __launch_bounds__(1024) void count_loss_kernel(
    const float* __restrict__ assigned, float* __restrict__ out, int N) {
  __shared__ unsigned hist[16][64];
  const int tid = threadIdx.x;
  const int wid = tid >> 6;
  hist[wid][tid & 63] = 0u;
  __syncthreads();
  const float4* src = (const float4*)assigned;
  for (int i = tid; i < (N >> 2); i += 1024) {
    float4 v = src[i];
    int e0 = (int)v.x, e1 = (int)v.y, e2 = (int)v.z, e3 = (int)v.w;
    if (e0 >= 0) atomicAdd(&hist[wid][e0], 1u);
    if (e1 >= 0) atomicAdd(&hist[wid][e1], 1u);
    if (e2 >= 0) atomicAdd(&hist[wid][e2], 1u);
    if (e3 >= 0) atomicAdd(&hist[wid][e3], 1u);
  }
  __syncthreads();
  if (tid < 64) {
    unsigned c = 0;
#pragma unroll
    for (int w = 0; w < 16; ++w) c += hist[w][tid];
    double cd = (double)c;
    double s = cd;
#pragma unroll
    for (int off = 32; off; off >>= 1) s += __shfl_xor(s, off);
    double mean = s / 64.0;
    double d = cd - mean;
    d = d * d;
#pragma unroll
    for (int off = 32; off; off >>= 1) d += __shfl_xor(d, off);
    if (tid == 0) out[3 * (size_t)N] = (float)((d / 64.0) / (mean + 1e-9));
  }
}

extern "C" void kernel_launch(void* const* d_in, const int* in_sizes, int n_in,
                              void* d_out, int out_size, void* d_ws, size_t ws_size,
                              hipStream_t stream) {
  const float* x = (const float*)d_in[0];
  const float* W = (const float*)d_in[1];
  const float* b = (const float*)d_in[2];

  const int E = in_sizes[2];      // 64
  const int D = in_sizes[1] / E;  // 1024
  const int N = in_sizes[0] / D;  // 32768

  int k = (int)((double)N / (double)(E > 1 ? E : 1) * 1.2);
  if (k < 1) k = 1;
  if (k > N) k = N;               // 614

  const size_t NE = (size_t)N * E;
  float* out = (float*)d_out;

  float* logits = (float*)d_ws;        // N*E fp32 (8 MB)
  float* logitsT = logits + NE;        // N*E fp32 (8 MB)
  unsigned* ukeys = (unsigned*)(logitsT + NE);

  logits_fused_kernel<<<N / 64, 1024, 0, stream>>>(x, W, b, logits, logitsT,
                                                   N, D);
  if (N == 32768)
    select_kernel<8><<<64, 1024, 0, stream>>>(logitsT, ukeys, N, k);
  else
    select_kernel<0><<<64, 1024, 0, stream>>>(logitsT, ukeys, N, k);
  assign_kernel<<<N / 4, 256, 0, stream>>>(logits, ukeys, out, N);
  count_loss_kernel<<<1, 1024, 0, stream>>>(out + N, out, N);
}